// Round 1
// 265.831 us; speedup vs baseline: 1.0293x; 1.0293x over previous
//
#include <hip/hip_runtime.h>
#include <hip/hip_bf16.h>
#include <cstdint>
#include <cstddef>

#define D 768
#define BATCH 8
#define LC 2048
#define LQ 1024
#define SCALE 0.03608439182435161f /* 1/sqrt(768) */

typedef __attribute__((ext_vector_type(8))) short short8;
typedef __attribute__((ext_vector_type(4))) float floatx4;

__device__ __forceinline__ short f2bf(float f) {
    union { float f; uint32_t u; } v; v.f = f;
    uint32_t r = v.u + 0x7fffu + ((v.u >> 16) & 1u);
    return (short)(r >> 16);
}

// ---- async global->LDS, 16B per lane ----
__device__ __forceinline__ void gl_lds16(const short* g, short* l) {
    __builtin_amdgcn_global_load_lds(
        reinterpret_cast<const __attribute__((address_space(1))) unsigned int*>(
            reinterpret_cast<uintptr_t>(g)),
        reinterpret_cast<__attribute__((address_space(3))) unsigned int*>(
            reinterpret_cast<uintptr_t>(l)),
        16, 0, 0);
}

// ================= old 128x128 core (kept for gemm1) =================
__device__ __forceinline__ void stage_tile(const short* gbase, int ld, int m0, int k0,
                                           short* lds, int tid) {
    const int r = tid >> 2, kc = (tid & 3) * 8;
    gl_lds16(gbase + (size_t)(m0 + r) * ld + k0 + kc, lds + tid * 8);
    gl_lds16(gbase + (size_t)(m0 + r + 64) * ld + k0 + kc, lds + 2048 + tid * 8);
}

__device__ __forceinline__ void mfma_tile_loop(
    const short* Ab, const short* Bb, int lda, int ldb, int K, int m0, int n0,
    short* sA, short* sB, int tid, floatx4 acc[4][4]) {
    const int w = tid >> 6, lane = tid & 63, l15 = lane & 15, quad = lane >> 4;
    const int wm = (w >> 1) * 64, wn = (w & 1) * 64;
    for (int k0 = 0; k0 < K; k0 += 32) {
        stage_tile(Ab, lda, m0, k0, sA, tid);
        stage_tile(Bb, ldb, n0, k0, sB, tid);
        __syncthreads();
        short8 af[4], bf[4];
#pragma unroll
        for (int mt = 0; mt < 4; ++mt)
            af[mt] = *reinterpret_cast<const short8*>(&sA[(wm + mt * 16 + l15) * 32 + quad * 8]);
#pragma unroll
        for (int nt = 0; nt < 4; ++nt)
            bf[nt] = *reinterpret_cast<const short8*>(&sB[(wn + nt * 16 + l15) * 32 + quad * 8]);
#pragma unroll
        for (int mt = 0; mt < 4; ++mt)
#pragma unroll
            for (int nt = 0; nt < 4; ++nt)
                acc[mt][nt] = __builtin_amdgcn_mfma_f32_16x16x32_bf16(af[mt], bf[nt], acc[mt][nt], 0, 0, 0);
        __syncthreads();
    }
}

// ================= new 256x256 core: BK=32, 3-deep counted-vmcnt pipeline =================
// C[256,256] = A[256,K] * B[256,K]^T, both row-major. 512 thr = 8 waves (2 wm x 4 wn).
// LDS: 3 buffers x (A 256x32 + B 256x32) bf16 = 96 KiB, 16B-chunk XOR swizzle slot^=(row&3)
// applied on BOTH the global stage source and the ds_read address (involution; rule #21).
// Schedule per K-tile kt: [vmcnt(4) gate][s_barrier][fence] stage A(kt+2) | read afx8,bfx2 |
// 16 MFMA | stage B(kt+2) | read bfx2 | 16 MFMA [fence]. Tile kt+1 stays in flight across
// the gate (counted vmcnt, never a full drain until the tail).
__device__ __forceinline__ void gemm256_loop(
    const short* __restrict__ A, const short* __restrict__ B,
    int lda, int ldb, int K, int m0, int n0,
    short* lds, int tid, floatx4 acc[8][4]) {
    const int lane = tid & 63, l15 = lane & 15, quad = lane >> 4;
    const int w = tid >> 6, wm = w >> 2, wn = w & 3;

    // staging: thread covers 16B chunks c0, c1 of each operand tile (1024 chunks = 256r x 4slots)
    const int c0 = tid, c1 = tid + 512;
    const int r0 = c0 >> 2, s0 = (c0 & 3) ^ (r0 & 3);
    const int r1 = c1 >> 2, s1 = (c1 & 3) ^ (r1 & 3);
    const short* gA0 = A + (size_t)(m0 + r0) * lda + s0 * 8;
    const short* gA1 = A + (size_t)(m0 + r1) * lda + s1 * 8;
    const short* gB0 = B + (size_t)(n0 + r0) * ldb + s0 * 8;
    const short* gB1 = B + (size_t)(n0 + r1) * ldb + s1 * 8;
    short* dA0 = lds + c0 * 8;
    short* dA1 = lds + c1 * 8;
    short* dB0 = lds + 8192 + c0 * 8;
    short* dB1 = lds + 8192 + c1 * 8;

    // ds_read offsets (shorts), swizzled: addr = row*32 + (quad ^ (row&3))*8
    int aoff[8], boff[4];
#pragma unroll
    for (int mt = 0; mt < 8; ++mt) {
        int r = wm * 128 + mt * 16 + l15;
        aoff[mt] = r * 32 + ((quad ^ (r & 3)) * 8);
    }
#pragma unroll
    for (int nt = 0; nt < 4; ++nt) {
        int r = wn * 64 + nt * 16 + l15;
        boff[nt] = 8192 + r * 32 + ((quad ^ (r & 3)) * 8);
    }

    const int NT = K >> 5;
#define STAGE_A(t, bb) { gl_lds16(gA0 + (t) * 32, dA0 + (bb)); gl_lds16(gA1 + (t) * 32, dA1 + (bb)); }
#define STAGE_B(t, bb) { gl_lds16(gB0 + (t) * 32, dB0 + (bb)); gl_lds16(gB1 + (t) * 32, dB1 + (bb)); }
    // prologue: tiles 0 and 1 (8 loads/thread in flight)
    STAGE_A(0, 0) STAGE_B(0, 0)
    STAGE_A(1, 16384) STAGE_B(1, 16384)

    for (int kt = 0; kt < NT; ++kt) {
        const int cur = (kt % 3) * 16384;
        const int nxt = ((kt + 2) % 3) * 16384;
        // gate: tile kt landed; tile kt+1 (4 newest loads) stays in flight
        if (kt + 1 < NT) { asm volatile("s_waitcnt vmcnt(4)" ::: "memory"); }
        else             { asm volatile("s_waitcnt vmcnt(0)" ::: "memory"); }
        __builtin_amdgcn_s_barrier();          // raw barrier: no implicit vmcnt(0) drain
        __builtin_amdgcn_sched_barrier(0);     // nothing hoists above the gate

        if (kt + 2 < NT) STAGE_A((kt + 2), nxt)  // target buffer fully read 1 tile ago

        short8 af[8], bf[4];
#pragma unroll
        for (int mt = 0; mt < 8; ++mt)
            af[mt] = *reinterpret_cast<const short8*>(lds + cur + aoff[mt]);
#pragma unroll
        for (int nt = 0; nt < 2; ++nt)
            bf[nt] = *reinterpret_cast<const short8*>(lds + cur + boff[nt]);
        __builtin_amdgcn_s_setprio(1);
#pragma unroll
        for (int mt = 0; mt < 8; ++mt)
#pragma unroll
            for (int nt = 0; nt < 2; ++nt)
                acc[mt][nt] = __builtin_amdgcn_mfma_f32_16x16x32_bf16(af[mt], bf[nt], acc[mt][nt], 0, 0, 0);
        __builtin_amdgcn_s_setprio(0);

        if (kt + 2 < NT) STAGE_B((kt + 2), nxt)

#pragma unroll
        for (int nt = 2; nt < 4; ++nt)
            bf[nt] = *reinterpret_cast<const short8*>(lds + cur + boff[nt]);
        __builtin_amdgcn_s_setprio(1);
#pragma unroll
        for (int mt = 0; mt < 8; ++mt)
#pragma unroll
            for (int nt = 2; nt < 4; ++nt)
                acc[mt][nt] = __builtin_amdgcn_mfma_f32_16x16x32_bf16(af[mt], bf[nt], acc[mt][nt], 0, 0, 0);
        __builtin_amdgcn_s_setprio(0);
        __builtin_amdgcn_sched_barrier(0);     // nothing sinks below this tile
    }
#undef STAGE_A
#undef STAGE_B
}

// ---------------- cast W fp32 -> bf16, and zero the row-sum buffer ----------------
__global__ void cast_w_kernel(const float* __restrict__ src, short* __restrict__ dst,
                              float* __restrict__ sums) {
    int i = blockIdx.x * 256 + threadIdx.x;
    if (i < 4096) {
        float4 z = {0.f, 0.f, 0.f, 0.f};
        reinterpret_cast<float4*>(sums)[i] = z;
    }
    float4 v = reinterpret_cast<const float4*>(src)[i];
    short4 o;
    o.x = f2bf(v.x); o.y = f2bf(v.y); o.z = f2bf(v.z); o.w = f2bf(v.w);
    reinterpret_cast<short4*>(dst)[i] = o;
}

// ---------------- qh pass: read qh once -> qh_b (bf16) + qhT (bf16 transposed) ----------------
__global__ void qh_pass_kernel(const float* __restrict__ qh, short* __restrict__ qh_b,
                               short* __restrict__ qhT) {
    __shared__ float tile[32][33];
    const int b = blockIdx.z;
    const int q0 = blockIdx.x * 32, d0 = blockIdx.y * 32;
    const int t = threadIdx.x;
    const int r = t >> 3, c = (t & 7) * 4;
    const float4 v = *reinterpret_cast<const float4*>(qh + ((size_t)b * LQ + q0 + r) * D + d0 + c);
    tile[r][c] = v.x; tile[r][c + 1] = v.y; tile[r][c + 2] = v.z; tile[r][c + 3] = v.w;
    short4 d;
    d.x = f2bf(v.x); d.y = f2bf(v.y); d.z = f2bf(v.z); d.w = f2bf(v.w);
    *reinterpret_cast<short4*>(qh_b + ((size_t)b * LQ + q0 + r) * D + d0 + c) = d;
    __syncthreads();
    short4 o;
    o.x = f2bf(tile[c][r]); o.y = f2bf(tile[c + 1][r]);
    o.z = f2bf(tile[c + 2][r]); o.w = f2bf(tile[c + 3][r]);
    *reinterpret_cast<short4*>(qhT + ((size_t)b * D + d0 + r) * LQ + q0 + c) = o;
}

// ---------------- GEMM1: query = qh_b * W_b^T + bias -> bf16 (old 128x128 path) ----------------
__global__ __launch_bounds__(256, 2) void gemm1_kernel(
    const short* __restrict__ A, const short* __restrict__ W,
    const float* __restrict__ bias, short* __restrict__ Q) {
    __shared__ short sA[128 * 32];
    __shared__ short sB[128 * 32];
    const int m0 = blockIdx.x * 128, n0 = blockIdx.y * 128;
    const int tid = threadIdx.x;
    const int w = tid >> 6, lane = tid & 63, l15 = lane & 15, quad = lane >> 4;
    const int wm = (w >> 1) * 64, wn = (w & 1) * 64;
    floatx4 acc[4][4];
#pragma unroll
    for (int i = 0; i < 4; ++i)
#pragma unroll
        for (int j = 0; j < 4; ++j) { floatx4 z = {0.f, 0.f, 0.f, 0.f}; acc[i][j] = z; }
    mfma_tile_loop(A, W, D, D, D, m0, n0, sA, sB, tid, acc);
    float bv[4];
#pragma unroll
    for (int nt = 0; nt < 4; ++nt) bv[nt] = bias[n0 + wn + nt * 16 + l15];
#pragma unroll
    for (int mt = 0; mt < 4; ++mt)
#pragma unroll
        for (int r = 0; r < 4; ++r) {
            int row = m0 + wm + mt * 16 + quad * 4 + r;
#pragma unroll
            for (int nt = 0; nt < 4; ++nt)
                Q[(size_t)row * D + n0 + wn + nt * 16 + l15] = f2bf(acc[mt][nt][r] + bv[nt]);
        }
}

// ---------------- ctx pass: copy ctx into out[:, :, 0:768] AND cast to bf16 ----------------
__global__ void ctx_pass_kernel(const float* __restrict__ ctx, float* __restrict__ out,
                                short* __restrict__ ctxb) {
    size_t i = (size_t)blockIdx.x * 256 + threadIdx.x;
    size_t row = i / 192;
    size_t c4 = i % 192;
    float4 v = reinterpret_cast<const float4*>(ctx)[i];
    reinterpret_cast<float4*>(out)[row * 384 + c4] = v;
    short4 o;
    o.x = f2bf(v.x); o.y = f2bf(v.y); o.z = f2bf(v.z); o.w = f2bf(v.w);
    reinterpret_cast<short4*>(ctxb)[i] = o;
}

// ---------------- K1 (256^2): P_unnorm = mask ? exp(scale*ctx*query^T) : 0 + row sums ----------------
__global__ __launch_bounds__(512, 2) void scores256_kernel(
    const short* __restrict__ ctxb, const short* __restrict__ query_b,
    const int* __restrict__ qmask, short* __restrict__ P, float* __restrict__ sums) {
    __shared__ __align__(16) short lds[3 * 16384];  // 96 KiB
    // XCD swizzle: each XCD owns one batch (32 blocks/batch)
    const int nb = ((blockIdx.x & 7) << 5) + (blockIdx.x >> 3);
    const int b = nb >> 5, rem = nb & 31, by = rem >> 3, bx = rem & 7;
    const int m0 = bx << 8, n0 = by << 8;
    const int tid = threadIdx.x;
    const int lane = tid & 63, l15 = lane & 15, quad = lane >> 4;
    const int w = tid >> 6, wm = w >> 2, wn = w & 3;

    floatx4 acc[8][4];
#pragma unroll
    for (int i = 0; i < 8; ++i)
#pragma unroll
        for (int j = 0; j < 4; ++j) { floatx4 z = {0.f, 0.f, 0.f, 0.f}; acc[i][j] = z; }

    gemm256_loop(ctxb + (size_t)b * LC * D, query_b + (size_t)b * LQ * D,
                 D, D, D, m0, n0, lds, tid, acc);

    const int* mk = qmask + b * LQ;
    bool valid[4];
#pragma unroll
    for (int nt = 0; nt < 4; ++nt) valid[nt] = (mk[n0 + wn * 64 + nt * 16 + l15] != 0);
    short* Pb = P + (size_t)b * LC * LQ;
    float* sumb = sums + (size_t)b * LC;
#pragma unroll
    for (int mt = 0; mt < 8; ++mt)
#pragma unroll
        for (int rr = 0; rr < 4; ++rr) {
            int row = m0 + wm * 128 + mt * 16 + quad * 4 + rr;
            float psum = 0.f;
#pragma unroll
            for (int nt = 0; nt < 4; ++nt) {
                float pv = valid[nt] ? __expf(acc[mt][nt][rr] * SCALE) : 0.f;
                psum += pv;
                Pb[(size_t)row * LQ + n0 + wn * 64 + nt * 16 + l15] = f2bf(pv);
            }
#pragma unroll
            for (int off = 1; off < 16; off <<= 1)
                psum += __shfl_xor(psum, off, 64);
            if (l15 == 0)
                atomicAdd(&sumb[row], psum);
        }
}

// ---------------- K2 (256^2): attn_out = (P_unnorm * qhT^T) / rowsum -> out[...,768:] ----------------
__global__ __launch_bounds__(512, 2) void gemm2_256_kernel(
    const short* __restrict__ P, const short* __restrict__ qhT,
    const float* __restrict__ sums, float* __restrict__ out) {
    __shared__ __align__(16) short lds[3 * 16384];  // 96 KiB
    // XCD swizzle: each XCD owns one batch (24 blocks/batch)
    const int nb = (blockIdx.x & 7) * 24 + (blockIdx.x >> 3);
    const int b = nb / 24, rem = nb % 24, by = rem >> 3, bx = rem & 7;
    const int m0 = bx << 8, n0 = by << 8;
    const int tid = threadIdx.x;
    const int lane = tid & 63, l15 = lane & 15, quad = lane >> 4;
    const int w = tid >> 6, wm = w >> 2, wn = w & 3;

    floatx4 acc[8][4];
#pragma unroll
    for (int i = 0; i < 8; ++i)
#pragma unroll
        for (int j = 0; j < 4; ++j) { floatx4 z = {0.f, 0.f, 0.f, 0.f}; acc[i][j] = z; }

    gemm256_loop(P + (size_t)b * LC * LQ, qhT + (size_t)b * D * LQ,
                 LQ, LQ, LQ, m0, n0, lds, tid, acc);

    const float* sumb = sums + (size_t)b * LC;
#pragma unroll
    for (int mt = 0; mt < 8; ++mt)
#pragma unroll
        for (int rr = 0; rr < 4; ++rr) {
            int lrow = m0 + wm * 128 + mt * 16 + quad * 4 + rr;
            const float inv = 1.0f / sumb[lrow];
            size_t rowoff = ((size_t)b * LC + lrow) * 1536 + 768;
#pragma unroll
            for (int nt = 0; nt < 4; ++nt)
                out[rowoff + n0 + wn * 64 + nt * 16 + l15] = acc[mt][nt][rr] * inv;
        }
}

extern "C" void kernel_launch(void* const* d_in, const int* in_sizes, int n_in,
                              void* d_out, int out_size, void* d_ws, size_t ws_size,
                              hipStream_t stream) {
    const float* ctx = (const float*)d_in[0];
    const float* qh = (const float*)d_in[2];
    const int* qmask = (const int*)d_in[3];
    const float* Wf = (const float*)d_in[4];
    const float* bias = (const float*)d_in[5];
    float* out = (float*)d_out;

    char* ws = (char*)d_ws;
    short* W_b     = (short*)(ws);                  //  1,179,648 B
    short* query_b = (short*)(ws + 1179648);        // 12,582,912 B
    short* qhT     = (short*)(ws + 13762560);       // 12,582,912 B
    short* ctx_b   = (short*)(ws + 26345472);       // 25,165,824 B
    short* P       = (short*)(ws + 51511296);       // 33,554,432 B
    float* sums    = (float*)(ws + 85065728);       //     65,536 B -> end 85,131,264
    short* qh_b    = (short*)(ws + 51511296);       // alias with P (dead before scores writes P)

    cast_w_kernel<<<576, 256, 0, stream>>>(Wf, W_b, sums);
    qh_pass_kernel<<<dim3(32, 24, 8), 256, 0, stream>>>(qh, qh_b, qhT);
    ctx_pass_kernel<<<12288, 256, 0, stream>>>(ctx, out, ctx_b);
    gemm1_kernel<<<dim3(64, 6), 256, 0, stream>>>(qh_b, W_b, bias, query_b);
    scores256_kernel<<<dim3(256), dim3(512), 0, stream>>>(ctx_b, query_b, qmask, P, sums);
    gemm2_256_kernel<<<dim3(192), dim3(512), 0, stream>>>(P, qhT, sums, out);
}